// Round 3
// baseline (904.616 us; speedup 1.0000x reference)
//
#include <hip/hip_runtime.h>
#include <hip/hip_cooperative_groups.h>
#include <math.h>

namespace cg = cooperative_groups;

#define N_ATOM 2048
#define NTOK   512
#define CC     128
#define CZDIM  16
#define HH     4
#define CHD    32
#define NHID   256
#define NC     (N_ATOM * CC)      // 262144
#define PBSZ   1048576            // 64*4*32*128 per transformer block

__device__ __forceinline__ float sigm(float x) { return 1.0f / (1.0f + __expf(-x)); }

struct MP {
    const float *ql, *cl, *plm, *a2t, *tm;
    const float *gs1, *ws1, *bs1, *wsb1;
    const float *wq, *bq, *wk, *wv;
    const float *gz, *bz, *wz;
    const float *wg, *wo, *wog1, *bog1;
    const float *gs2, *ws2, *bs2, *wsb2;
    const float *wt1, *wt2, *wt3, *wog2, *bog2;
    float *qbuf, *kbuf, *vbuf, *obuf;   // each [2][NC] (parity double-buffer)
    float *pb, *amask;
    float *out;
};

// One cooperative kernel: grid 256 x 256 threads, 1 block/CU.
// Block owns atom rows [bid*8, bid*8+8). Wave w owns rows {2w, 2w+1}.
__global__ __launch_bounds__(256, 1) void k_mega(MP p) {
    // persistent across phases
    __shared__ float arow[8][CC];     // current 'a' rows (updated in P3)
    __shared__ float cls[8][CC];      // raw cl rows
    __shared__ float cn[8][CC];       // LN(cl), unscaled
    __shared__ float sn1[8][CC];      // LN(cl)*gs1[b]
    __shared__ float sn2[8][CC];      // LN(cl)*gs2[b]
    __shared__ float lna[8][CC];      // LN(a)  (reused as gos in P3)
    __shared__ float aln1[8][CC];
    __shared__ float a2s[8][CC];
    __shared__ float hid[8][NHID];
    __shared__ float gsh[8][CC];      // sigmoid(g)
    __shared__ float og1sh[8][CC];    // sigmoid(og1)
    __shared__ float transsh[8][CC];  // transition output
    // attention scratch
    __shared__ __align__(16) float qs[32][36];
    __shared__ __align__(16) float ks[128][36];
    __shared__ __align__(16) float vs[128][36];
    __shared__ float ps[32][132];

    cg::grid_group grid = cg::this_grid();
    const int t = threadIdx.x, bid = blockIdx.x;
    const int w = t >> 6, l = t & 63;
    const int r0 = 2 * w, r1 = 2 * w + 1;
    const int o2 = 2 * l;
    const int n0 = bid * 8;

    // ---------------- setup: cls + cn = LN(cl) ----------------
    for (int idx = t; idx < 8 * CC; idx += 256)
        cls[idx >> 7][idx & 127] = p.cl[(size_t)n0 * CC + idx];
    __syncthreads();
#pragma unroll
    for (int rr = 0; rr < 2; rr++) {
        int r = 2 * w + rr;
        float x0 = cls[r][l], x1 = cls[r][l + 64];
        float s = x0 + x1, s2 = x0 * x0 + x1 * x1;
#pragma unroll
        for (int m = 1; m < 64; m <<= 1) { s += __shfl_xor(s, m); s2 += __shfl_xor(s2, m); }
        float mean = s * (1.0f / 128.0f);
        float rs = rsqrtf(s2 * (1.0f / 128.0f) - mean * mean + 1e-5f);
        cn[r][l] = (x0 - mean) * rs; cn[r][l + 64] = (x1 - mean) * rs;
    }

    // ---------------- P0: amask + pair bias (all 3 blocks) ----------------
    {
        int lrow = bid * 8 + (t >> 5);
        int ln32 = t & 31;
        float s = 0.0f;
        for (int j = ln32; j < NTOK; j += 32) s += p.a2t[(size_t)lrow * NTOK + j] * p.tm[j];
#pragma unroll
        for (int m = 1; m < 32; m <<= 1) s += __shfl_xor(s, m);
        if (ln32 == 0) p.amask[lrow] = (s - 1.0f) * 1e9f;
    }
    for (int pid = bid * 256 + t; pid < 3 * 262144; pid += 65536) {
        int b = pid >> 18;
        int rem = pid & 262143;
        int qb = rem >> 12;
        int qi = (rem >> 7) & 31;
        int kj = rem & 127;
        int n = qb * 32 + qi;
        int kstart = max(0, qb * 32 - 48);
        int m = kstart + kj;
        const float* gzb = p.gz + b * CZDIM;
        const float* bzb = p.bz + b * CZDIM;
        const float* wzb = p.wz + b * CZDIM * HH;
        float out[HH] = {0, 0, 0, 0};
        if (m < N_ATOM) {
            const float4* p4 = (const float4*)(p.plm + ((size_t)n * N_ATOM + m) * CZDIM);
            float x[CZDIM];
#pragma unroll
            for (int i = 0; i < 4; i++) {
                float4 v = p4[i];
                x[4 * i] = v.x; x[4 * i + 1] = v.y; x[4 * i + 2] = v.z; x[4 * i + 3] = v.w;
            }
            float s = 0, s2 = 0;
#pragma unroll
            for (int c = 0; c < CZDIM; c++) { s += x[c]; s2 += x[c] * x[c]; }
            float mean = s * (1.0f / 16.0f);
            float rs = rsqrtf(s2 * (1.0f / 16.0f) - mean * mean + 1e-5f);
#pragma unroll
            for (int c = 0; c < CZDIM; c++) {
                float z = (x[c] - mean) * rs * gzb[c] + bzb[c];
#pragma unroll
                for (int h = 0; h < HH; h++) out[h] += z * wzb[c * HH + h];
            }
        }
#pragma unroll
        for (int h = 0; h < HH; h++)
            p.pb[(size_t)b * PBSZ + (((qb * HH + h) * 32 + qi) << 7) + kj] = out[h];
    }
    grid.sync();

    // ---------------- 3 transformer blocks ----------------
    for (int b = 0; b < 3; b++) {
        float* qcur = p.qbuf + (size_t)(b & 1) * NC;
        float* kcur = p.kbuf + (size_t)(b & 1) * NC;
        float* vcur = p.vbuf + (size_t)(b & 1) * NC;
        float* ocur = p.obuf + (size_t)(b & 1) * NC;

        // ======== P1: AdaLN x2 + q/k/v/g + og1/og2 + SwiGLU transition ========
        {
            const float* gs1b = p.gs1 + b * CC;
            const float* gs2b = p.gs2 + b * CC;
            for (int idx = t; idx < 8 * CC; idx += 256) {
                int r = idx >> 7, c = idx & 127;
                float cv = cn[r][c];
                sn1[r][c] = cv * gs1b[c];
                sn2[r][c] = cv * gs2b[c];
            }
            if (b == 0) {
                for (int idx = t; idx < 8 * CC; idx += 256)
                    arow[idx >> 7][idx & 127] = p.ql[(size_t)n0 * CC + idx];
            }
            __syncthreads();

            // LN(a) on own rows
#pragma unroll
            for (int rr = 0; rr < 2; rr++) {
                int r = 2 * w + rr;
                float x0 = arow[r][l], x1 = arow[r][l + 64];
                float s = x0 + x1, s2 = x0 * x0 + x1 * x1;
#pragma unroll
                for (int m = 1; m < 64; m <<= 1) { s += __shfl_xor(s, m); s2 += __shfl_xor(s2, m); }
                float mean = s * (1.0f / 128.0f);
                float rs = rsqrtf(s2 * (1.0f / 128.0f) - mean * mean + 1e-5f);
                lna[r][l] = (x0 - mean) * rs; lna[r][l + 64] = (x1 - mean) * rs;
            }

            // ---- Stage A: both AdaLN matmuls (2 rows x 2 cols per thread) ----
            {
                const float* ws1b = p.ws1 + b * CC * CC;
                const float* wsb1b = p.wsb1 + b * CC * CC;
                const float* ws2b = p.ws2 + b * CC * CC;
                const float* wsb2b = p.wsb2 + b * CC * CC;
                float A1ax = 0, A1ay = 0, A1bx = 0, A1by = 0;
                float B1ax = 0, B1ay = 0, B1bx = 0, B1by = 0;
                float A2ax = 0, A2ay = 0, A2bx = 0, A2by = 0;
                float B2ax = 0, B2ay = 0, B2bx = 0, B2by = 0;
#pragma unroll 4
                for (int c = 0; c < CC; c++) {
                    float2 w1 = *(const float2*)(ws1b + c * CC + o2);
                    float2 wb1 = *(const float2*)(wsb1b + c * CC + o2);
                    float2 w2 = *(const float2*)(ws2b + c * CC + o2);
                    float2 wb2 = *(const float2*)(wsb2b + c * CC + o2);
                    float x1a = sn1[r0][c], x1b = sn1[r1][c];
                    float x2a = sn2[r0][c], x2b = sn2[r1][c];
                    A1ax += x1a * w1.x;  A1ay += x1a * w1.y;
                    A1bx += x1b * w1.x;  A1by += x1b * w1.y;
                    B1ax += x1a * wb1.x; B1ay += x1a * wb1.y;
                    B1bx += x1b * wb1.x; B1by += x1b * wb1.y;
                    A2ax += x2a * w2.x;  A2ay += x2a * w2.y;
                    A2bx += x2b * w2.x;  A2by += x2b * w2.y;
                    B2ax += x2a * wb2.x; B2ay += x2a * wb2.y;
                    B2bx += x2b * wb2.x; B2by += x2b * wb2.y;
                }
                const float* bs1b = p.bs1 + b * CC;
                const float* bs2b = p.bs2 + b * CC;
                float bb0 = bs1b[o2], bb1 = bs1b[o2 + 1];
                float cb0 = bs2b[o2], cb1 = bs2b[o2 + 1];
                aln1[r0][o2]     = sigm(A1ax + bb0) * lna[r0][o2]     + B1ax;
                aln1[r0][o2 + 1] = sigm(A1ay + bb1) * lna[r0][o2 + 1] + B1ay;
                aln1[r1][o2]     = sigm(A1bx + bb0) * lna[r1][o2]     + B1bx;
                aln1[r1][o2 + 1] = sigm(A1by + bb1) * lna[r1][o2 + 1] + B1by;
                a2s[r0][o2]      = sigm(A2ax + cb0) * lna[r0][o2]     + B2ax;
                a2s[r0][o2 + 1]  = sigm(A2ay + cb1) * lna[r0][o2 + 1] + B2ay;
                a2s[r1][o2]      = sigm(A2bx + cb0) * lna[r1][o2]     + B2bx;
                a2s[r1][o2 + 1]  = sigm(A2by + cb1) * lna[r1][o2 + 1] + B2by;
            }

            // ---- Stage B: q,k,v,g from aln1; og1,og2 from raw cl ----
            float G2ax, G2ay, G2bx, G2by;  // og2 pre-activation for stage D
            {
                const float* wqb = p.wq + b * CC * CC;
                const float* wkb = p.wk + b * CC * CC;
                const float* wvb = p.wv + b * CC * CC;
                const float* wgb = p.wg + b * CC * CC;
                const float* wog1b = p.wog1 + b * CC * CC;
                const float* wog2b = p.wog2 + b * CC * CC;
                float Aqax = 0, Aqay = 0, Aqbx = 0, Aqby = 0;
                float Akax = 0, Akay = 0, Akbx = 0, Akby = 0;
                float Avax = 0, Avay = 0, Avbx = 0, Avby = 0;
                float Agax = 0, Agay = 0, Agbx = 0, Agby = 0;
                float O1ax = 0, O1ay = 0, O1bx = 0, O1by = 0;
                float O2ax = 0, O2ay = 0, O2bx = 0, O2by = 0;
#pragma unroll 4
                for (int c = 0; c < CC; c++) {
                    float xa = aln1[r0][c], xb = aln1[r1][c];
                    float ca = cls[r0][c], cb = cls[r1][c];
                    float2 wqv = *(const float2*)(wqb + c * CC + o2);
                    float2 wkv = *(const float2*)(wkb + c * CC + o2);
                    float2 wvv = *(const float2*)(wvb + c * CC + o2);
                    float2 wgv = *(const float2*)(wgb + c * CC + o2);
                    float2 w1v = *(const float2*)(wog1b + c * CC + o2);
                    float2 w2v = *(const float2*)(wog2b + c * CC + o2);
                    Aqax += xa * wqv.x; Aqay += xa * wqv.y; Aqbx += xb * wqv.x; Aqby += xb * wqv.y;
                    Akax += xa * wkv.x; Akay += xa * wkv.y; Akbx += xb * wkv.x; Akby += xb * wkv.y;
                    Avax += xa * wvv.x; Avay += xa * wvv.y; Avbx += xb * wvv.x; Avby += xb * wvv.y;
                    Agax += xa * wgv.x; Agay += xa * wgv.y; Agbx += xb * wgv.x; Agby += xb * wgv.y;
                    O1ax += ca * w1v.x; O1ay += ca * w1v.y; O1bx += cb * w1v.x; O1by += cb * w1v.y;
                    O2ax += ca * w2v.x; O2ay += ca * w2v.y; O2bx += cb * w2v.x; O2by += cb * w2v.y;
                }
                const float* bqb = p.bq + b * CC;
                const float* bog1b = p.bog1 + b * CC;
                float q0 = bqb[o2], q1 = bqb[o2 + 1];
                float g0 = bog1b[o2], g1 = bog1b[o2 + 1];
                size_t ba = (size_t)(n0 + r0) * CC + o2;
                size_t bb = (size_t)(n0 + r1) * CC + o2;
                *(float2*)(qcur + ba) = make_float2(Aqax + q0, Aqay + q1);
                *(float2*)(qcur + bb) = make_float2(Aqbx + q0, Aqby + q1);
                *(float2*)(kcur + ba) = make_float2(Akax, Akay);
                *(float2*)(kcur + bb) = make_float2(Akbx, Akby);
                *(float2*)(vcur + ba) = make_float2(Avax, Avay);
                *(float2*)(vcur + bb) = make_float2(Avbx, Avby);
                gsh[r0][o2] = sigm(Agax); gsh[r0][o2 + 1] = sigm(Agay);
                gsh[r1][o2] = sigm(Agbx); gsh[r1][o2 + 1] = sigm(Agby);
                og1sh[r0][o2] = sigm(O1ax + g0); og1sh[r0][o2 + 1] = sigm(O1ay + g1);
                og1sh[r1][o2] = sigm(O1bx + g0); og1sh[r1][o2 + 1] = sigm(O1by + g1);
                G2ax = O2ax; G2ay = O2ay; G2bx = O2bx; G2by = O2by;
            }

            // ---- Stage C: SwiGLU hidden ----
            {
                const float* wt1b = p.wt1 + b * CC * NHID;
                const float* wt2b = p.wt2 + b * CC * NHID;
                const int o4 = 4 * l;
                float T1a[4] = {0, 0, 0, 0}, T2a[4] = {0, 0, 0, 0};
                float T1b[4] = {0, 0, 0, 0}, T2b[4] = {0, 0, 0, 0};
#pragma unroll 4
                for (int c = 0; c < CC; c++) {
                    float xa = a2s[r0][c], xb = a2s[r1][c];
                    float4 w1v = *(const float4*)(wt1b + c * NHID + o4);
                    float4 w2v = *(const float4*)(wt2b + c * NHID + o4);
                    T1a[0] += xa * w1v.x; T1a[1] += xa * w1v.y; T1a[2] += xa * w1v.z; T1a[3] += xa * w1v.w;
                    T2a[0] += xa * w2v.x; T2a[1] += xa * w2v.y; T2a[2] += xa * w2v.z; T2a[3] += xa * w2v.w;
                    T1b[0] += xb * w1v.x; T1b[1] += xb * w1v.y; T1b[2] += xb * w1v.z; T1b[3] += xb * w1v.w;
                    T2b[0] += xb * w2v.x; T2b[1] += xb * w2v.y; T2b[2] += xb * w2v.z; T2b[3] += xb * w2v.w;
                }
                float4 ha, hb;
                ha.x = T1a[0] * sigm(T1a[0]) * T2a[0]; ha.y = T1a[1] * sigm(T1a[1]) * T2a[1];
                ha.z = T1a[2] * sigm(T1a[2]) * T2a[2]; ha.w = T1a[3] * sigm(T1a[3]) * T2a[3];
                hb.x = T1b[0] * sigm(T1b[0]) * T2b[0]; hb.y = T1b[1] * sigm(T1b[1]) * T2b[1];
                hb.z = T1b[2] * sigm(T1b[2]) * T2b[2]; hb.w = T1b[3] * sigm(T1b[3]) * T2b[3];
                *(float4*)&hid[r0][o4] = ha;
                *(float4*)&hid[r1][o4] = hb;
            }

            // ---- Stage D: trans = sigmoid(og2) * (hid @ wt3) ----
            {
                const float* wt3b = p.wt3 + b * NHID * CC;
                float Axa = 0, Aya = 0, Axb = 0, Ayb = 0;
#pragma unroll 8
                for (int c = 0; c < NHID; c++) {
                    float xa = hid[r0][c], xb = hid[r1][c];
                    float2 wv3 = *(const float2*)(wt3b + c * CC + o2);
                    Axa += xa * wv3.x; Aya += xa * wv3.y;
                    Axb += xb * wv3.x; Ayb += xb * wv3.y;
                }
                const float* bog2b = p.bog2 + b * CC;
                float b0 = bog2b[o2], b1 = bog2b[o2 + 1];
                transsh[r0][o2] = sigm(G2ax + b0) * Axa; transsh[r0][o2 + 1] = sigm(G2ay + b1) * Aya;
                transsh[r1][o2] = sigm(G2bx + b0) * Axb; transsh[r1][o2 + 1] = sigm(G2by + b1) * Ayb;
            }
        }
        grid.sync();

        // ======== P2: attention, (qb,h) = blockIdx ========
        {
            const int qb = bid >> 2, h = bid & 3;
            const int n0q = qb * 32;
            const int kstart = max(0, qb * 32 - 48);
            const int nk = min(N_ATOM, qb * 32 + 80) - kstart;
            const float* pbb = p.pb + (size_t)b * PBSZ;

            for (int idx = t; idx < 32 * 32; idx += 256) {
                int qi = idx >> 5, d = idx & 31;
                qs[qi][d] = qcur[(size_t)(n0q + qi) * CC + h * CHD + d];
            }
            for (int idx = t; idx < 128 * 32; idx += 256) {
                int kj = idx >> 5, d = idx & 31;
                int m = kstart + kj;
                float kv = 0.0f, vv = 0.0f;
                if (m < N_ATOM) {
                    kv = kcur[(size_t)m * CC + h * CHD + d];
                    vv = vcur[(size_t)m * CC + h * CHD + d];
                }
                ks[kj][d] = kv; vs[kj][d] = vv;
            }
            __syncthreads();

            const int qi = t >> 3, j8 = t & 7;
            float qreg[32];
#pragma unroll
            for (int i = 0; i < 8; i++) {
                float4 v4 = *(const float4*)&qs[qi][4 * i];
                qreg[4 * i] = v4.x; qreg[4 * i + 1] = v4.y; qreg[4 * i + 2] = v4.z; qreg[4 * i + 3] = v4.w;
            }
            const float isc = 0.17677669529663687f;
            const float* pbrow = pbb + ((qb * HH + h) * 32 + qi) * 128;
            float lr[16];
            float mx = -1e30f;
#pragma unroll
            for (int jj = 0; jj < 16; jj++) {
                int kj = j8 + 8 * jj;
                float acc = 0;
#pragma unroll
                for (int i = 0; i < 8; i++) {
                    float4 kv = *(const float4*)&ks[kj][4 * i];
                    acc += qreg[4 * i] * kv.x + qreg[4 * i + 1] * kv.y
                         + qreg[4 * i + 2] * kv.z + qreg[4 * i + 3] * kv.w;
                }
                float lg = (kj < nk) ? (acc * isc + pbrow[kj] + p.amask[kstart + kj]) : -1e9f;
                lr[jj] = lg;
                mx = fmaxf(mx, lg);
            }
#pragma unroll
            for (int m = 1; m < 8; m <<= 1) mx = fmaxf(mx, __shfl_xor(mx, m));
            float sum = 0;
#pragma unroll
            for (int jj = 0; jj < 16; jj++) { lr[jj] = __expf(lr[jj] - mx); sum += lr[jj]; }
#pragma unroll
            for (int m = 1; m < 8; m <<= 1) sum += __shfl_xor(sum, m);
            float rd = 1.0f / sum;
#pragma unroll
            for (int jj = 0; jj < 16; jj++) ps[qi][j8 + 8 * jj] = lr[jj] * rd;
            __syncthreads();

            const int d0 = (t & 7) * 4;
            float4 acc = {0, 0, 0, 0};
            for (int kj = 0; kj < 128; kj++) {
                float pp = ps[qi][kj];
                float4 vv = *(const float4*)&vs[kj][d0];
                acc.x += pp * vv.x; acc.y += pp * vv.y; acc.z += pp * vv.z; acc.w += pp * vv.w;
            }
            *(float4*)&ocur[(size_t)(n0q + qi) * CC + h * CHD + d0] = acc;
        }
        grid.sync();

        // ======== P3: a_new = og1 * ((g*o) @ wo) + trans  (row-local) ========
        {
            // gos into lna (scratch)
#pragma unroll
            for (int rr = 0; rr < 2; rr++) {
                int r = 2 * w + rr;
                const float* orow = ocur + (size_t)(n0 + r) * CC;
                lna[r][l] = gsh[r][l] * orow[l];
                lna[r][l + 64] = gsh[r][l + 64] * orow[l + 64];
            }
            const float* wob = p.wo + b * CC * CC;
            float Axa = 0, Aya = 0, Axb = 0, Ayb = 0;
#pragma unroll 4
            for (int c = 0; c < CC; c++) {
                float xa = lna[r0][c], xb = lna[r1][c];
                float2 wv = *(const float2*)(wob + c * CC + o2);
                Axa += xa * wv.x; Aya += xa * wv.y;
                Axb += xb * wv.x; Ayb += xb * wv.y;
            }
            float na0 = og1sh[r0][o2] * Axa + transsh[r0][o2];
            float na1 = og1sh[r0][o2 + 1] * Aya + transsh[r0][o2 + 1];
            float nb0 = og1sh[r1][o2] * Axb + transsh[r1][o2];
            float nb1 = og1sh[r1][o2 + 1] * Ayb + transsh[r1][o2 + 1];
            arow[r0][o2] = na0; arow[r0][o2 + 1] = na1;
            arow[r1][o2] = nb0; arow[r1][o2 + 1] = nb1;
            if (b == 2) {
                *(float2*)(p.out + (size_t)(n0 + r0) * CC + o2) = make_float2(na0, na1);
                *(float2*)(p.out + (size_t)(n0 + r1) * CC + o2) = make_float2(nb0, nb1);
            }
        }
        // no grid sync needed here: P1(b+1) writes qkv[(b+1)&1] / reads only
        // block-local LDS; laggard readers of this iteration's buffers are
        // protected by the parity double-buffer + the next two grid syncs.
    }
}

// ---------------------------------------------------------------------------
extern "C" void kernel_launch(void* const* d_in, const int* in_sizes, int n_in,
                              void* d_out, int out_size, void* d_ws, size_t ws_size,
                              hipStream_t stream) {
    MP p;
    p.ql   = (const float*)d_in[0];
    p.cl   = (const float*)d_in[1];
    p.plm  = (const float*)d_in[2];
    p.a2t  = (const float*)d_in[3];
    p.tm   = (const float*)d_in[4];
    p.gs1  = (const float*)d_in[5];
    p.ws1  = (const float*)d_in[6];
    p.bs1  = (const float*)d_in[7];
    p.wsb1 = (const float*)d_in[8];
    p.wq   = (const float*)d_in[9];
    p.bq   = (const float*)d_in[10];
    p.wk   = (const float*)d_in[11];
    p.wv   = (const float*)d_in[12];
    p.gz   = (const float*)d_in[13];
    p.bz   = (const float*)d_in[14];
    p.wz   = (const float*)d_in[15];
    p.wg   = (const float*)d_in[16];
    p.wo   = (const float*)d_in[17];
    p.wog1 = (const float*)d_in[18];
    p.bog1 = (const float*)d_in[19];
    p.gs2  = (const float*)d_in[20];
    p.ws2  = (const float*)d_in[21];
    p.bs2  = (const float*)d_in[22];
    p.wsb2 = (const float*)d_in[23];
    p.wt1  = (const float*)d_in[24];
    p.wt2  = (const float*)d_in[25];
    p.wt3  = (const float*)d_in[26];
    p.wog2 = (const float*)d_in[27];
    p.bog2 = (const float*)d_in[28];

    float* ws = (float*)d_ws;
    p.qbuf  = ws;
    p.kbuf  = ws + 2 * NC;
    p.vbuf  = ws + 4 * NC;
    p.obuf  = ws + 6 * NC;
    p.pb    = ws + 8 * NC;                 // 3 * PBSZ floats
    p.amask = ws + 8 * NC + 3 * PBSZ;      // 2048 floats
    p.out   = (float*)d_out;

    void* kargs[] = {(void*)&p};
    hipLaunchCooperativeKernel((const void*)k_mega, dim3(256), dim3(256),
                               kargs, 0, stream);
}

// Round 4
// 830.194 us; speedup vs baseline: 1.0896x; 1.0896x over previous
//
#include <hip/hip_runtime.h>
#include <math.h>

#define N_ATOM 2048
#define NTOK   512
#define CC     128
#define CZDIM  16
#define HH     4
#define CHD    32
#define NHID   256
#define NC     (N_ATOM * CC)
#define PBSZ   1048576   // 64*4*32*128 per transformer block

__device__ __forceinline__ float sigm(float x) { return 1.0f / (1.0f + __expf(-x)); }

// ---------------------------------------------------------------------------
// amask[l] = (sum_i a2t[l,i]*tm[i] - 1) * 1e9
__global__ __launch_bounds__(256) void k_amask(const float* __restrict__ a2t,
                                               const float* __restrict__ tm,
                                               float* __restrict__ amask) {
    int wave = threadIdx.x >> 6, lane = threadIdx.x & 63;
    int l = blockIdx.x * 4 + wave;
    float s = 0.0f;
    for (int i = lane; i < NTOK; i += 64) s += a2t[(size_t)l * NTOK + i] * tm[i];
#pragma unroll
    for (int m = 1; m < 64; m <<= 1) s += __shfl_xor(s, m);
    if (lane == 0) amask[l] = (s - 1.0f) * 1e9f;
}

// ---------------------------------------------------------------------------
// k_pre: pair bias for ALL 3 blocks, one plm read. 1 thread per (qb,qi,kj).
// grid 256 x 1024 = 262144 threads.
__global__ __launch_bounds__(1024) void k_pre(const float* __restrict__ plm,
                                              const float* __restrict__ gz,
                                              const float* __restrict__ bz,
                                              const float* __restrict__ wz,
                                              float* __restrict__ pb) {
    __shared__ float gzs[48], bzs[48], wzs[192];
    const int t = threadIdx.x;
    if (t < 48) gzs[t] = gz[t];
    else if (t < 96) bzs[t - 48] = bz[t - 48];
    else if (t < 288) wzs[t - 96] = wz[t - 96];
    __syncthreads();

    int pid = blockIdx.x * 1024 + t;
    int qb = pid >> 12;
    int qi = (pid >> 7) & 31;
    int kj = pid & 127;
    int n = qb * 32 + qi;
    int kstart = max(0, qb * 32 - 48);
    int m = kstart + kj;
    bool valid = (m < N_ATOM);
    float x[CZDIM];
    if (valid) {
        const float4* p4 = (const float4*)(plm + ((size_t)n * N_ATOM + m) * CZDIM);
#pragma unroll
        for (int i = 0; i < 4; i++) {
            float4 v = p4[i];
            x[4 * i] = v.x; x[4 * i + 1] = v.y; x[4 * i + 2] = v.z; x[4 * i + 3] = v.w;
        }
        float s = 0, s2 = 0;
#pragma unroll
        for (int c = 0; c < CZDIM; c++) { s += x[c]; s2 += x[c] * x[c]; }
        float mean = s * (1.0f / 16.0f);
        float rs = rsqrtf(s2 * (1.0f / 16.0f) - mean * mean + 1e-5f);
#pragma unroll
        for (int c = 0; c < CZDIM; c++) x[c] = (x[c] - mean) * rs;
    } else {
#pragma unroll
        for (int c = 0; c < CZDIM; c++) x[c] = 0.0f;
    }
#pragma unroll
    for (int b = 0; b < 3; b++) {
        float o0 = 0, o1 = 0, o2 = 0, o3 = 0;
#pragma unroll
        for (int c = 0; c < CZDIM; c++) {
            float z = x[c] * gzs[b * 16 + c] + (valid ? bzs[b * 16 + c] : 0.0f);
            const float* wr = &wzs[b * 64 + c * 4];
            o0 += z * wr[0]; o1 += z * wr[1]; o2 += z * wr[2]; o3 += z * wr[3];
        }
        float* dst = pb + (size_t)b * PBSZ + ((size_t)(qb * HH) * 32 + qi) * 128 + kj;
        dst[0]          = o0;
        dst[32 * 128]   = o1;
        dst[2 * 32 * 128] = o2;
        dst[3 * 32 * 128] = o3;
    }
}

// ---------------------------------------------------------------------------
// k13: [combine from previous block] + AdaLN x2 + q/k/v/g/og1/og2 + SwiGLU.
// grid 256 x 1024. Block owns 8 rows. wave w: r = w&7, grp = w>>3.
__global__ __launch_bounds__(1024) void k13(
    int has_combine,
    const float* __restrict__ a_in, const float* __restrict__ cl,
    const float* __restrict__ g_in, const float* __restrict__ o_in,
    const float* __restrict__ og1_in, const float* __restrict__ trans_in,
    const float* __restrict__ wo_prev,
    const float* __restrict__ gs1, const float* __restrict__ ws1,
    const float* __restrict__ bs1, const float* __restrict__ wsb1,
    const float* __restrict__ wq, const float* __restrict__ bq,
    const float* __restrict__ wk, const float* __restrict__ wv,
    const float* __restrict__ wg,
    const float* __restrict__ wog1, const float* __restrict__ bog1,
    const float* __restrict__ gs2, const float* __restrict__ ws2,
    const float* __restrict__ bs2, const float* __restrict__ wsb2,
    const float* __restrict__ wt1, const float* __restrict__ wt2,
    const float* __restrict__ wt3,
    const float* __restrict__ wog2, const float* __restrict__ bog2,
    float* __restrict__ q_o, float* __restrict__ k_o, float* __restrict__ v_o,
    float* __restrict__ g_o, float* __restrict__ og1_o, float* __restrict__ trans_o) {
    __shared__ float cls[8][CC], arow[8][CC], lna[8][CC];
    __shared__ float sn1[8][CC], sn2[8][CC], aln1[8][CC], a2s[8][CC];
    __shared__ __align__(16) float t1h[8][NHID], t2h[8][NHID];

    const int t = threadIdx.x, w = t >> 6, l = t & 63;
    const int r = w & 7, grp = w >> 3;
    const int n0 = blockIdx.x * 8;

    { // load cl rows (+ gos scratch into aln1, or a into arow)
        int rr = t >> 7, c = t & 127;
        size_t base = (size_t)(n0 + rr) * CC + c;
        cls[rr][c] = cl[base];
        if (has_combine) aln1[rr][c] = g_in[base] * o_in[base];
        else arow[rr][c] = a_in[base];
    }
    __syncthreads();

    if (has_combine) { // a_new = og1 * (gos @ wo_prev) + trans
        int o = grp * 64 + l;
        float A = 0;
#pragma unroll 4
        for (int c = 0; c < CC; c++) A += aln1[r][c] * wo_prev[c * CC + o];
        size_t base = (size_t)(n0 + r) * CC + o;
        arow[r][o] = og1_in[base] * A + trans_in[base];
        __syncthreads();
    }

    // LN: grp0 waves -> LN(arow row r) -> lna; grp1 waves -> LN(cls row r) -> sn1/sn2
    if (grp == 0) {
        float x0 = arow[r][l], x1 = arow[r][l + 64];
        float s = x0 + x1, s2 = x0 * x0 + x1 * x1;
#pragma unroll
        for (int m = 1; m < 64; m <<= 1) { s += __shfl_xor(s, m); s2 += __shfl_xor(s2, m); }
        float mean = s * (1.0f / 128.0f);
        float rs = rsqrtf(s2 * (1.0f / 128.0f) - mean * mean + 1e-5f);
        lna[r][l] = (x0 - mean) * rs; lna[r][l + 64] = (x1 - mean) * rs;
    } else {
        float x0 = cls[r][l], x1 = cls[r][l + 64];
        float s = x0 + x1, s2 = x0 * x0 + x1 * x1;
#pragma unroll
        for (int m = 1; m < 64; m <<= 1) { s += __shfl_xor(s, m); s2 += __shfl_xor(s2, m); }
        float mean = s * (1.0f / 128.0f);
        float rs = rsqrtf(s2 * (1.0f / 128.0f) - mean * mean + 1e-5f);
        float cn0 = (x0 - mean) * rs, cn1 = (x1 - mean) * rs;
        sn1[r][l] = cn0 * gs1[l]; sn1[r][l + 64] = cn1 * gs1[l + 64];
        sn2[r][l] = cn0 * gs2[l]; sn2[r][l + 64] = cn1 * gs2[l + 64];
    }
    __syncthreads();

    // Stage A: grp0: (ws1,wsb1)->aln1; grp1: (ws2,wsb2)->a2s. 2 cols/lane.
    {
        const float* wsA = grp ? ws2 : ws1;
        const float* wsB = grp ? wsb2 : wsb1;
        const float* bsb = grp ? bs2 : bs1;
        const float* snp = grp ? &sn2[r][0] : &sn1[r][0];
        const int o2 = 2 * l;
        float Ax = 0, Ay = 0, Bx = 0, By = 0;
#pragma unroll 4
        for (int c = 0; c < CC; c++) {
            float x = snp[c];
            float2 wa = *(const float2*)(wsA + c * CC + o2);
            float2 wb = *(const float2*)(wsB + c * CC + o2);
            Ax += x * wa.x; Ay += x * wa.y; Bx += x * wb.x; By += x * wb.y;
        }
        float lx = lna[r][o2], ly = lna[r][o2 + 1];
        float* dst = grp ? &a2s[r][0] : &aln1[r][0];
        dst[o2]     = sigm(Ax + bsb[o2]) * lx + Bx;
        dst[o2 + 1] = sigm(Ay + bsb[o2 + 1]) * ly + By;
    }
    __syncthreads();

    // Stage B: grp0: q,k,v from aln1 -> global. grp1: g from aln1, og1/og2 from cls.
    {
        const int o2 = 2 * l;
        if (grp == 0) {
            float Aqx = 0, Aqy = 0, Akx = 0, Aky = 0, Avx = 0, Avy = 0;
#pragma unroll 4
            for (int c = 0; c < CC; c++) {
                float x = aln1[r][c];
                float2 wqv = *(const float2*)(wq + c * CC + o2);
                float2 wkv = *(const float2*)(wk + c * CC + o2);
                float2 wvv = *(const float2*)(wv + c * CC + o2);
                Aqx += x * wqv.x; Aqy += x * wqv.y;
                Akx += x * wkv.x; Aky += x * wkv.y;
                Avx += x * wvv.x; Avy += x * wvv.y;
            }
            size_t base = (size_t)(n0 + r) * CC + o2;
            *(float2*)(q_o + base) = make_float2(Aqx + bq[o2], Aqy + bq[o2 + 1]);
            *(float2*)(k_o + base) = make_float2(Akx, Aky);
            *(float2*)(v_o + base) = make_float2(Avx, Avy);
        } else {
            float Agx = 0, Agy = 0, O1x = 0, O1y = 0, O2x = 0, O2y = 0;
#pragma unroll 4
            for (int c = 0; c < CC; c++) {
                float xa = aln1[r][c], xc = cls[r][c];
                float2 wgv = *(const float2*)(wg + c * CC + o2);
                float2 w1v = *(const float2*)(wog1 + c * CC + o2);
                float2 w2v = *(const float2*)(wog2 + c * CC + o2);
                Agx += xa * wgv.x; Agy += xa * wgv.y;
                O1x += xc * w1v.x; O1y += xc * w1v.y;
                O2x += xc * w2v.x; O2y += xc * w2v.y;
            }
            size_t base = (size_t)(n0 + r) * CC + o2;
            *(float2*)(g_o + base)   = make_float2(sigm(Agx), sigm(Agy));
            *(float2*)(og1_o + base) = make_float2(sigm(O1x + bog1[o2]), sigm(O1y + bog1[o2 + 1]));
            sn2[r][o2] = O2x; sn2[r][o2 + 1] = O2y;   // og2 preact (sn2 dead after stage A)
        }
    }

    // Stage C: grp0: wt1 -> t1h; grp1: wt2 -> t2h. 4 cols/lane, float4 loads.
    {
        const float* wt = grp ? wt2 : wt1;
        const int o4 = 4 * l;
        float T0 = 0, T1 = 0, T2 = 0, T3 = 0;
#pragma unroll 4
        for (int c = 0; c < CC; c++) {
            float x = a2s[r][c];
            float4 wv4 = *(const float4*)(wt + c * NHID + o4);
            T0 += x * wv4.x; T1 += x * wv4.y; T2 += x * wv4.z; T3 += x * wv4.w;
        }
        float* dst = grp ? &t2h[r][0] : &t1h[r][0];
        *(float4*)&dst[o4] = make_float4(T0, T1, T2, T3);
    }
    __syncthreads();

    { // elementwise: t1h = silu(t1h) * t2h  (2 elems/thread)
        int rr = t >> 7, c2 = (t & 127) * 2;
        float x0 = t1h[rr][c2], x1 = t1h[rr][c2 + 1];
        t1h[rr][c2]     = x0 * sigm(x0) * t2h[rr][c2];
        t1h[rr][c2 + 1] = x1 * sigm(x1) * t2h[rr][c2 + 1];
    }
    __syncthreads();

    // Stage D: trans = sigmoid(og2 + bog2) * (hid @ wt3). 1 col/lane.
    {
        int o = grp * 64 + l;
        float A = 0;
#pragma unroll 4
        for (int c = 0; c < NHID; c++) A += t1h[r][c] * wt3[c * CC + o];
        trans_o[(size_t)(n0 + r) * CC + o] = sigm(sn2[r][o] + bog2[o]) * A;
    }
}

// ---------------------------------------------------------------------------
// k_attn: one block per (qb,h), 1024 threads (16 waves/CU).
__global__ __launch_bounds__(1024) void k_attn(const float* __restrict__ q,
                                               const float* __restrict__ k,
                                               const float* __restrict__ v,
                                               const float* __restrict__ pb,
                                               const float* __restrict__ amask,
                                               float* __restrict__ o_out) {
    __shared__ float qs[32][33];
    __shared__ __align__(16) float ks[128][36];
    __shared__ __align__(16) float vs[128][36];
    __shared__ float ps[32][128];
    const int t = threadIdx.x;
    const int qb = blockIdx.x >> 2, h = blockIdx.x & 3;
    const int n0 = qb * 32;
    const int kstart = max(0, qb * 32 - 48);
    const int nk = min(N_ATOM, qb * 32 + 80) - kstart;

    { int qi = t >> 5, d = t & 31; qs[qi][d] = q[(size_t)(n0 + qi) * CC + h * CHD + d]; }
    for (int idx = t; idx < 128 * 32; idx += 1024) {
        int kj = idx >> 5, d = idx & 31;
        int m = kstart + kj;
        float kv = 0.0f, vv = 0.0f;
        if (m < N_ATOM) {
            kv = k[(size_t)m * CC + h * CHD + d];
            vv = v[(size_t)m * CC + h * CHD + d];
        }
        ks[kj][d] = kv; vs[kj][d] = vv;
    }
    __syncthreads();

    const int qi = t >> 5, j32 = t & 31;
    float qreg[32];
#pragma unroll
    for (int i = 0; i < 32; i++) qreg[i] = qs[qi][i];
    const float isc = 0.17677669529663687f;  // 1/sqrt(32)
    const float* pbrow = pb + ((size_t)(qb * HH + h) * 32 + qi) * 128;
    float lr[4];
    float mx = -1e30f;
#pragma unroll
    for (int jj = 0; jj < 4; jj++) {
        int kj = j32 + 32 * jj;
        float acc = 0;
#pragma unroll
        for (int i = 0; i < 8; i++) {
            float4 kv = *(const float4*)&ks[kj][4 * i];
            acc += qreg[4 * i] * kv.x + qreg[4 * i + 1] * kv.y
                 + qreg[4 * i + 2] * kv.z + qreg[4 * i + 3] * kv.w;
        }
        float lg = (kj < nk) ? (acc * isc + pbrow[kj] + amask[kstart + kj]) : -1e9f;
        lr[jj] = lg;
        mx = fmaxf(mx, lg);
    }
#pragma unroll
    for (int m = 1; m < 32; m <<= 1) mx = fmaxf(mx, __shfl_xor(mx, m));
    float sum = 0;
#pragma unroll
    for (int jj = 0; jj < 4; jj++) { lr[jj] = __expf(lr[jj] - mx); sum += lr[jj]; }
#pragma unroll
    for (int m = 1; m < 32; m <<= 1) sum += __shfl_xor(sum, m);
    float rd = 1.0f / sum;
#pragma unroll
    for (int jj = 0; jj < 4; jj++) ps[qi][j32 + 32 * jj] = lr[jj] * rd;
    __syncthreads();

    const int d = t & 31;
    float acc = 0;
    for (int kj = 0; kj < 128; kj++) acc += ps[qi][kj] * vs[kj][d];
    o_out[(size_t)(n0 + qi) * CC + h * CHD + d] = acc;
}

// ---------------------------------------------------------------------------
// k3f: final combine -> d_out. grid 256 x 1024.
__global__ __launch_bounds__(1024) void k3f(const float* __restrict__ g_in,
                                            const float* __restrict__ o_in,
                                            const float* __restrict__ og1_in,
                                            const float* __restrict__ trans_in,
                                            const float* __restrict__ wo_prev,
                                            float* __restrict__ out) {
    __shared__ float gos[8][CC];
    const int t = threadIdx.x, w = t >> 6, l = t & 63;
    const int r = w & 7, grp = w >> 3;
    const int n0 = blockIdx.x * 8;
    {
        int rr = t >> 7, c = t & 127;
        size_t base = (size_t)(n0 + rr) * CC + c;
        gos[rr][c] = g_in[base] * o_in[base];
    }
    __syncthreads();
    int o = grp * 64 + l;
    float A = 0;
#pragma unroll 4
    for (int c = 0; c < CC; c++) A += gos[r][c] * wo_prev[c * CC + o];
    size_t base = (size_t)(n0 + r) * CC + o;
    out[base] = og1_in[base] * A + trans_in[base];
}

// ---------------------------------------------------------------------------
extern "C" void kernel_launch(void* const* d_in, const int* in_sizes, int n_in,
                              void* d_out, int out_size, void* d_ws, size_t ws_size,
                              hipStream_t stream) {
    const float* ql   = (const float*)d_in[0];
    const float* cl   = (const float*)d_in[1];
    const float* plm  = (const float*)d_in[2];
    const float* a2t  = (const float*)d_in[3];
    const float* tm   = (const float*)d_in[4];
    const float* ada1_gs  = (const float*)d_in[5];
    const float* ada1_ws  = (const float*)d_in[6];
    const float* ada1_bs  = (const float*)d_in[7];
    const float* ada1_wsb = (const float*)d_in[8];
    const float* wq  = (const float*)d_in[9];
    const float* bq  = (const float*)d_in[10];
    const float* wk  = (const float*)d_in[11];
    const float* wv  = (const float*)d_in[12];
    const float* gz  = (const float*)d_in[13];
    const float* bz  = (const float*)d_in[14];
    const float* wz  = (const float*)d_in[15];
    const float* wg  = (const float*)d_in[16];
    const float* wo  = (const float*)d_in[17];
    const float* wog1 = (const float*)d_in[18];
    const float* bog1 = (const float*)d_in[19];
    const float* ada2_gs  = (const float*)d_in[20];
    const float* ada2_ws  = (const float*)d_in[21];
    const float* ada2_bs  = (const float*)d_in[22];
    const float* ada2_wsb = (const float*)d_in[23];
    const float* wt1 = (const float*)d_in[24];
    const float* wt2 = (const float*)d_in[25];
    const float* wt3 = (const float*)d_in[26];
    const float* wog2 = (const float*)d_in[27];
    const float* bog2 = (const float*)d_in[28];

    float* ws = (float*)d_ws;
    float* qb_    = ws;
    float* kb_    = ws + 1 * NC;
    float* vb_    = ws + 2 * NC;
    float* gb_    = ws + 3 * NC;
    float* og1b_  = ws + 4 * NC;
    float* transb = ws + 5 * NC;
    float* ob_    = ws + 6 * NC;
    float* pbb_   = ws + 7 * NC;               // 3 * PBSZ
    float* amaskb = ws + 7 * NC + 3 * PBSZ;    // 2048

    k_amask<<<N_ATOM / 4, 256, 0, stream>>>(a2t, tm, amaskb);
    k_pre<<<256, 1024, 0, stream>>>(plm, gz, bz, wz, pbb_);

    for (int b = 0; b < 3; b++) {
        k13<<<256, 1024, 0, stream>>>(
            (b > 0) ? 1 : 0,
            ql, cl, gb_, ob_, og1b_, transb,
            (b > 0) ? (wo + (b - 1) * CC * CC) : wo,
            ada1_gs + b * CC, ada1_ws + b * CC * CC, ada1_bs + b * CC, ada1_wsb + b * CC * CC,
            wq + b * CC * CC, bq + b * CC, wk + b * CC * CC, wv + b * CC * CC, wg + b * CC * CC,
            wog1 + b * CC * CC, bog1 + b * CC,
            ada2_gs + b * CC, ada2_ws + b * CC * CC, ada2_bs + b * CC, ada2_wsb + b * CC * CC,
            wt1 + b * CC * NHID, wt2 + b * CC * NHID, wt3 + b * NHID * CC,
            wog2 + b * CC * CC, bog2 + b * CC,
            qb_, kb_, vb_, gb_, og1b_, transb);
        k_attn<<<64 * HH, 1024, 0, stream>>>(qb_, kb_, vb_, pbb_ + (size_t)b * PBSZ,
                                             amaskb, ob_);
    }
    k3f<<<256, 1024, 0, stream>>>(gb_, ob_, og1b_, transb, wo + 2 * CC * CC,
                                  (float*)d_out);
}